// Round 6
// baseline (163.085 us; speedup 1.0000x reference)
//
#include <hip/hip_runtime.h>

#define N_NODES 10000
#define N_PAIRS 1200000
#define DIM 128
#define ROW4 2500          // float4 per dist row (10000 floats)
#define SEG_BLOCKS 4688    // ceil(N_PAIRS/256)
#define FW_BLOCKS 625      // 10000 rows / (4 waves * 4 rows)

__device__ inline float bf2f(unsigned short u) {
    return __uint_as_float(((unsigned int)u) << 16);
}
__device__ inline unsigned short f2bf(float f) {
    unsigned int i = __float_as_uint(f);
    return (unsigned short)((i + 0x7FFFu + ((i >> 16) & 1u)) >> 16);   // RNE
}
__device__ inline float rl_f(float v, int q) {
    return __uint_as_float(__builtin_amdgcn_readlane(__float_as_uint(v), q));
}

// ---------- Prep: blocks [0,SEG_BLOCKS) build seg[]; rest compute FW=F@W (bf16) ----------
__global__ __launch_bounds__(256, 4)
void prep_kernel(const int* __restrict__ pair_node, int* __restrict__ seg,
                 const float* __restrict__ F, const float* __restrict__ W,
                 ushort2* __restrict__ FWb2)
{
    const int bid = blockIdx.x;
    if (bid < SEG_BLOCKS) {
        const int p = bid * 256 + threadIdx.x;
        if (p >= N_PAIRS) return;
        const int cur  = pair_node[p];
        const int prev = (p == 0) ? -1 : pair_node[p - 1];
        for (int n = prev + 1; n <= cur; ++n) seg[n] = p;
        if (p == N_PAIRS - 1)
            for (int n = cur + 1; n <= N_NODES; ++n) seg[n] = N_PAIRS;
        return;
    }

    // FW GEMM: wave per 4 rows, register-only, W streamed from L2.
    const int fb   = bid - SEG_BLOCKS;
    const int wid  = threadIdx.x >> 6;
    const int lane = threadIdx.x & 63;
    const int m0   = (fb * 4 + wid) * 4;
    if (m0 >= N_NODES) return;

    const float2* F2 = (const float2*)F;
    const float2* W2 = (const float2*)W;

    const float2 f0 = F2[(size_t)(m0 + 0) * 64 + lane];
    const float2 f1 = F2[(size_t)(m0 + 1) * 64 + lane];
    const float2 f2 = F2[(size_t)(m0 + 2) * 64 + lane];
    const float2 f3 = F2[(size_t)(m0 + 3) * 64 + lane];

    float2 a0 = {0.f, 0.f}, a1 = {0.f, 0.f}, a2 = {0.f, 0.f}, a3 = {0.f, 0.f};

    #pragma unroll 4
    for (int kk = 0; kk < 64; ++kk) {
        const float2 wa = W2[(size_t)(2 * kk + 0) * 64 + lane];
        const float2 wb = W2[(size_t)(2 * kk + 1) * 64 + lane];
        const float s0x = rl_f(f0.x, kk), s0y = rl_f(f0.y, kk);
        const float s1x = rl_f(f1.x, kk), s1y = rl_f(f1.y, kk);
        const float s2x = rl_f(f2.x, kk), s2y = rl_f(f2.y, kk);
        const float s3x = rl_f(f3.x, kk), s3y = rl_f(f3.y, kk);
        a0.x += s0x * wa.x + s0y * wb.x;  a0.y += s0x * wa.y + s0y * wb.y;
        a1.x += s1x * wa.x + s1y * wb.x;  a1.y += s1x * wa.y + s1y * wb.y;
        a2.x += s2x * wa.x + s2y * wb.x;  a2.y += s2x * wa.y + s2y * wb.y;
        a3.x += s3x * wa.x + s3y * wb.x;  a3.y += s3x * wa.y + s3y * wb.y;
    }

    ushort2 o;
    o.x = f2bf(a0.x); o.y = f2bf(a0.y); FWb2[(size_t)(m0 + 0) * 64 + lane] = o;
    o.x = f2bf(a1.x); o.y = f2bf(a1.y); FWb2[(size_t)(m0 + 1) * 64 + lane] = o;
    o.x = f2bf(a2.x); o.y = f2bf(a2.y); FWb2[(size_t)(m0 + 2) * 64 + lane] = o;
    o.x = f2bf(a3.x); o.y = f2bf(a3.y); FWb2[(size_t)(m0 + 3) * 64 + lane] = o;
}

// ---------- Fused: block-per-node. Stream dist row -> LDS (coalesced), pair weights
// from LDS gathers, readlane-broadcast accumulation of w*(FW[i]+FW[j]) over 8 waves. ----------
__global__ __launch_bounds__(512, 4)
void fused_kernel(const float* __restrict__ dist,
                  const ushort2* __restrict__ FW2,   // [N_NODES][64]
                  const int* __restrict__ seg,
                  const int* __restrict__ pair_i,
                  const int* __restrict__ pair_j,
                  const float* __restrict__ pair_cos,
                  const float* __restrict__ b,
                  float* __restrict__ out)
{
    __shared__ float sRow[N_NODES];   // 40000 B; aliased for the final reduce

    const int n    = blockIdx.x;
    const int tid  = threadIdx.x;
    const int wid  = tid >> 6;
    const int lane = tid & 63;

    // ---- stream row n into LDS (perfectly coalesced float4) ----
    const float4* dist4 = (const float4*)dist + (size_t)n * ROW4;
    float4* sRow4 = (float4*)sRow;
    for (int t = tid; t < ROW4; t += 512)
        sRow4[t] = dist4[t];

    const int lo  = seg[n];
    const int hi  = seg[n + 1];

    __syncthreads();   // row ready

    float a0 = 0.f, a1 = 0.f;

    for (int base = lo; base < hi; base += 512) {
        const int m   = min(512, hi - base);
        const int per = (m + 7) >> 3;                    // pairs per wave (<=64)
        const int s   = base + wid * per;
        const int myc = max(0, min(s + per, base + m) - s);

        // phase A: lane l < myc computes w for pair s+l (LDS gathers)
        int il = 0, jl = 0; float wl = 0.f;
        if (lane < myc) {
            const int p = s + lane;
            il = pair_i[p];
            jl = pair_j[p];
            wl = pair_cos[p] * sRow[il] * sRow[jl];
        }

        // phase B: broadcast each pair; all 64 lanes cover dims {2*lane, 2*lane+1}
        #pragma unroll 4
        for (int q = 0; q < myc; ++q) {
            const int   iq = __builtin_amdgcn_readlane(il, q);
            const int   jq = __builtin_amdgcn_readlane(jl, q);
            const float wq = rl_f(wl, q);
            const ushort2 fi = FW2[(size_t)iq * 64 + lane];
            const ushort2 fj = FW2[(size_t)jq * 64 + lane];
            a0 += wq * (bf2f(fi.x) + bf2f(fj.x));
            a1 += wq * (bf2f(fi.y) + bf2f(fj.y));
        }
    }

    // ---- cross-wave reduce (alias sRow; all row reads are done) ----
    __syncthreads();
    float2* sAcc2 = (float2*)sRow;     // [8][64] float2
    sAcc2[wid * 64 + lane] = make_float2(a0, a1);
    __syncthreads();

    if (tid < 64) {
        float2 t = sAcc2[tid];
        #pragma unroll
        for (int w2 = 1; w2 < 8; ++w2) {
            const float2 v = sAcc2[w2 * 64 + tid];
            t.x += v.x; t.y += v.y;
        }
        const float2 bb = ((const float2*)b)[tid];
        ((float2*)out)[(size_t)n * 64 + tid] = make_float2(t.x + bb.x, t.y + bb.y);
    }
}

extern "C" void kernel_launch(void* const* d_in, const int* in_sizes, int n_in,
                              void* d_out, int out_size, void* d_ws, size_t ws_size,
                              hipStream_t stream) {
    const float* features  = (const float*)d_in[0];
    const float* dist      = (const float*)d_in[1];
    const int*   pair_node = (const int*)  d_in[2];
    const int*   pair_i    = (const int*)  d_in[3];
    const int*   pair_j    = (const int*)  d_in[4];
    const float* pair_cos  = (const float*)d_in[5];
    const float* W         = (const float*)d_in[6];
    const float* b         = (const float*)d_in[7];
    float* out = (float*)d_out;

    // workspace: seg int[N_NODES+1] (padded to 40960 B), then FW bf16 (2.56 MB)
    int* seg = (int*)d_ws;
    ushort2* FWb2 = (ushort2*)((char*)d_ws + 10240 * sizeof(int));

    prep_kernel<<<SEG_BLOCKS + FW_BLOCKS, 256, 0, stream>>>(pair_node, seg, features, W, FWb2);
    fused_kernel<<<N_NODES, 512, 0, stream>>>(
        dist, FWb2, seg, pair_i, pair_j, pair_cos, b, out);
}

// Round 7
// 112.330 us; speedup vs baseline: 1.4518x; 1.4518x over previous
//
#include <hip/hip_runtime.h>

#define N_NODES 10000
#define N_PAIRS 1200000
#define DIM 128

__device__ inline float bf2f(unsigned short u) {
    return __uint_as_float(((unsigned int)u) << 16);
}
__device__ inline unsigned short f2bf(float f) {
    unsigned int i = __float_as_uint(f);
    return (unsigned short)((i + 0x7FFFu + ((i >> 16) & 1u)) >> 16);   // RNE
}
__device__ inline float rl_f(float v, int q) {
    return __uint_as_float(__builtin_amdgcn_readlane(__float_as_uint(v), q));
}

// ---------- Kernel 0: segment starts. seg[n] = first pair index with node >= n. ----------
__global__ __launch_bounds__(256)
void seg_start_kernel(const int* __restrict__ pair_node, int* __restrict__ seg) {
    const int p = blockIdx.x * 256 + threadIdx.x;
    if (p >= N_PAIRS) return;
    const int cur  = pair_node[p];
    const int prev = (p == 0) ? -1 : pair_node[p - 1];
    for (int n = prev + 1; n <= cur; ++n) seg[n] = p;
    if (p == N_PAIRS - 1)
        for (int n = cur + 1; n <= N_NODES; ++n) seg[n] = N_PAIRS;
}

// ---------- Kernel A: FW = F @ W (bf16 out). Wave-per-4-rows, register-only. ----------
__global__ __launch_bounds__(256, 4)
void fw_gemm_kernel(const float* __restrict__ F, const float* __restrict__ W,
                    ushort2* __restrict__ FWb2)
{
    const int wid  = threadIdx.x >> 6;
    const int lane = threadIdx.x & 63;
    const int m0   = (blockIdx.x * 4 + wid) * 4;
    if (m0 >= N_NODES) return;

    const float2* F2 = (const float2*)F;
    const float2* W2 = (const float2*)W;

    const float2 f0 = F2[(size_t)(m0 + 0) * 64 + lane];
    const float2 f1 = F2[(size_t)(m0 + 1) * 64 + lane];
    const float2 f2 = F2[(size_t)(m0 + 2) * 64 + lane];
    const float2 f3 = F2[(size_t)(m0 + 3) * 64 + lane];

    float2 a0 = {0.f, 0.f}, a1 = {0.f, 0.f}, a2 = {0.f, 0.f}, a3 = {0.f, 0.f};

    #pragma unroll 4
    for (int kk = 0; kk < 64; ++kk) {
        const float2 wa = W2[(size_t)(2 * kk + 0) * 64 + lane];
        const float2 wb = W2[(size_t)(2 * kk + 1) * 64 + lane];
        const float s0x = rl_f(f0.x, kk), s0y = rl_f(f0.y, kk);
        const float s1x = rl_f(f1.x, kk), s1y = rl_f(f1.y, kk);
        const float s2x = rl_f(f2.x, kk), s2y = rl_f(f2.y, kk);
        const float s3x = rl_f(f3.x, kk), s3y = rl_f(f3.y, kk);
        a0.x += s0x * wa.x + s0y * wb.x;  a0.y += s0x * wa.y + s0y * wb.y;
        a1.x += s1x * wa.x + s1y * wb.x;  a1.y += s1x * wa.y + s1y * wb.y;
        a2.x += s2x * wa.x + s2y * wb.x;  a2.y += s2x * wa.y + s2y * wb.y;
        a3.x += s3x * wa.x + s3y * wb.x;  a3.y += s3x * wa.y + s3y * wb.y;
    }

    ushort2 o;
    o.x = f2bf(a0.x); o.y = f2bf(a0.y); FWb2[(size_t)(m0 + 0) * 64 + lane] = o;
    o.x = f2bf(a1.x); o.y = f2bf(a1.y); FWb2[(size_t)(m0 + 1) * 64 + lane] = o;
    o.x = f2bf(a2.x); o.y = f2bf(a2.y); FWb2[(size_t)(m0 + 2) * 64 + lane] = o;
    o.x = f2bf(a3.x); o.y = f2bf(a3.y); FWb2[(size_t)(m0 + 3) * 64 + lane] = o;
}

// ---------- Fused: wave-per-node, barrier-free, LDS-free ----------
// Phase A: ALL of the node's dist gathers issued in one burst (<=3 chunks of 64 pairs
// held in registers) so same-line requests dedup in L1/L2 MSHRs before eviction.
// Phase B: readlane-broadcast each pair; lane accumulates dims {2*lane, 2*lane+1}.
__global__ __launch_bounds__(256, 8)
void fused_seg_kernel(const float* __restrict__ dist,
                      const ushort2* __restrict__ FW2,   // [N_NODES][64]
                      const int* __restrict__ seg,
                      const int* __restrict__ pair_i,
                      const int* __restrict__ pair_j,
                      const float* __restrict__ pair_cos,
                      const float* __restrict__ b,
                      float* __restrict__ out)
{
    const int wid  = threadIdx.x >> 6;
    const int lane = threadIdx.x & 63;
    const int n    = blockIdx.x * 4 + wid;     // grid = 2500 x 4 waves = 10000
    const int lo = seg[n];
    const int hi = seg[n + 1];
    const size_t drow = (size_t)n * N_NODES;

    float a0 = 0.f, a1 = 0.f;

    for (int base = lo; base < hi; base += 192) {
        // ---- phase A: up to 3 pairs per lane; all gathers in one burst ----
        const int p0 = base + lane, p1 = p0 + 64, p2 = p0 + 128;
        const bool v0 = p0 < hi, v1 = p1 < hi, v2 = p2 < hi;

        int i0 = 0, j0 = 0, i1 = 0, j1 = 0, i2 = 0, j2 = 0;
        if (v0) { i0 = pair_i[p0]; j0 = pair_j[p0]; }
        if (v1) { i1 = pair_i[p1]; j1 = pair_j[p1]; }
        if (v2) { i2 = pair_i[p2]; j2 = pair_j[p2]; }

        float di0 = 0.f, dj0 = 0.f, di1 = 0.f, dj1 = 0.f, di2 = 0.f, dj2 = 0.f;
        float c0 = 0.f, c1 = 0.f, c2 = 0.f;
        if (v0) { di0 = dist[drow + i0]; dj0 = dist[drow + j0]; c0 = pair_cos[p0]; }
        if (v1) { di1 = dist[drow + i1]; dj1 = dist[drow + j1]; c1 = pair_cos[p1]; }
        if (v2) { di2 = dist[drow + i2]; dj2 = dist[drow + j2]; c2 = pair_cos[p2]; }

        const float w0 = c0 * di0 * dj0;
        const float w1 = c1 * di1 * dj1;
        const float w2 = c2 * di2 * dj2;

        // ---- phase B: broadcast each pair, gather FW rows (L2), accumulate ----
        const int m  = min(192, hi - base);
        const int q0max = min(64, m);
        const int q1max = max(0, min(64, m - 64));
        const int q2max = max(0, min(64, m - 128));

        #pragma unroll 8
        for (int q = 0; q < q0max; ++q) {
            const int   iq = __builtin_amdgcn_readlane(i0, q);
            const int   jq = __builtin_amdgcn_readlane(j0, q);
            const float wq = rl_f(w0, q);
            const ushort2 fi = FW2[(size_t)iq * 64 + lane];
            const ushort2 fj = FW2[(size_t)jq * 64 + lane];
            a0 += wq * (bf2f(fi.x) + bf2f(fj.x));
            a1 += wq * (bf2f(fi.y) + bf2f(fj.y));
        }
        #pragma unroll 8
        for (int q = 0; q < q1max; ++q) {
            const int   iq = __builtin_amdgcn_readlane(i1, q);
            const int   jq = __builtin_amdgcn_readlane(j1, q);
            const float wq = rl_f(w1, q);
            const ushort2 fi = FW2[(size_t)iq * 64 + lane];
            const ushort2 fj = FW2[(size_t)jq * 64 + lane];
            a0 += wq * (bf2f(fi.x) + bf2f(fj.x));
            a1 += wq * (bf2f(fi.y) + bf2f(fj.y));
        }
        #pragma unroll 8
        for (int q = 0; q < q2max; ++q) {
            const int   iq = __builtin_amdgcn_readlane(i2, q);
            const int   jq = __builtin_amdgcn_readlane(j2, q);
            const float wq = rl_f(w2, q);
            const ushort2 fi = FW2[(size_t)iq * 64 + lane];
            const ushort2 fj = FW2[(size_t)jq * 64 + lane];
            a0 += wq * (bf2f(fi.x) + bf2f(fj.x));
            a1 += wq * (bf2f(fi.y) + bf2f(fj.y));
        }
    }

    const float2 bb = ((const float2*)b)[lane];
    ((float2*)out)[(size_t)n * 64 + lane] = make_float2(a0 + bb.x, a1 + bb.y);
}

extern "C" void kernel_launch(void* const* d_in, const int* in_sizes, int n_in,
                              void* d_out, int out_size, void* d_ws, size_t ws_size,
                              hipStream_t stream) {
    const float* features  = (const float*)d_in[0];
    const float* dist      = (const float*)d_in[1];
    const int*   pair_node = (const int*)  d_in[2];
    const int*   pair_i    = (const int*)  d_in[3];
    const int*   pair_j    = (const int*)  d_in[4];
    const float* pair_cos  = (const float*)d_in[5];
    const float* W         = (const float*)d_in[6];
    const float* b         = (const float*)d_in[7];
    float* out = (float*)d_out;

    // workspace: seg int[N_NODES+1] (padded to 40960 B), then FW bf16 (2.56 MB)
    int* seg = (int*)d_ws;
    ushort2* FWb2 = (ushort2*)((char*)d_ws + 10240 * sizeof(int));

    seg_start_kernel<<<(N_PAIRS + 255) / 256, 256, 0, stream>>>(pair_node, seg);
    fw_gemm_kernel<<<N_NODES / 16, 256, 0, stream>>>(features, W, FWb2);
    fused_seg_kernel<<<N_NODES / 4, 256, 0, stream>>>(
        dist, FWb2, seg, pair_i, pair_j, pair_cos, b, out);
}

// Round 8
// 109.246 us; speedup vs baseline: 1.4928x; 1.0282x over previous
//
#include <hip/hip_runtime.h>

#define N_NODES 10000
#define N_PAIRS 1200000
#define DIM 128
#define SEG_BLOCKS 4688    // ceil(N_PAIRS/256)
#define FW_BLOCKS 625      // 10000 rows / (4 waves * 4 rows)

__device__ inline float bf2f(unsigned short u) {
    return __uint_as_float(((unsigned int)u) << 16);
}
__device__ inline unsigned short f2bf(float f) {
    unsigned int i = __float_as_uint(f);
    return (unsigned short)((i + 0x7FFFu + ((i >> 16) & 1u)) >> 16);   // RNE
}
__device__ inline float rl_f(float v, int q) {
    return __uint_as_float(__builtin_amdgcn_readlane(__float_as_uint(v), q));
}

// ---------- Prep: blocks [0,SEG_BLOCKS) build seg[]; rest compute FW = F @ W (bf16). ----------
__global__ __launch_bounds__(256, 4)
void prep_kernel(const int* __restrict__ pair_node, int* __restrict__ seg,
                 const float* __restrict__ F, const float* __restrict__ W,
                 ushort2* __restrict__ FWb2)
{
    const int bid = blockIdx.x;
    if (bid < SEG_BLOCKS) {
        const int p = bid * 256 + threadIdx.x;
        if (p >= N_PAIRS) return;
        const int cur  = pair_node[p];
        const int prev = (p == 0) ? -1 : pair_node[p - 1];
        for (int n = prev + 1; n <= cur; ++n) seg[n] = p;
        if (p == N_PAIRS - 1)
            for (int n = cur + 1; n <= N_NODES; ++n) seg[n] = N_PAIRS;
        return;
    }

    // FW GEMM: wave per 4 rows, register-only, W streamed from L2.
    const int fb   = bid - SEG_BLOCKS;
    const int wid  = threadIdx.x >> 6;
    const int lane = threadIdx.x & 63;
    const int m0   = (fb * 4 + wid) * 4;
    if (m0 >= N_NODES) return;

    const float2* F2 = (const float2*)F;
    const float2* W2 = (const float2*)W;

    const float2 f0 = F2[(size_t)(m0 + 0) * 64 + lane];
    const float2 f1 = F2[(size_t)(m0 + 1) * 64 + lane];
    const float2 f2 = F2[(size_t)(m0 + 2) * 64 + lane];
    const float2 f3 = F2[(size_t)(m0 + 3) * 64 + lane];

    float2 a0 = {0.f, 0.f}, a1 = {0.f, 0.f}, a2 = {0.f, 0.f}, a3 = {0.f, 0.f};

    #pragma unroll 4
    for (int kk = 0; kk < 64; ++kk) {
        const float2 wa = W2[(size_t)(2 * kk + 0) * 64 + lane];
        const float2 wb = W2[(size_t)(2 * kk + 1) * 64 + lane];
        const float s0x = rl_f(f0.x, kk), s0y = rl_f(f0.y, kk);
        const float s1x = rl_f(f1.x, kk), s1y = rl_f(f1.y, kk);
        const float s2x = rl_f(f2.x, kk), s2y = rl_f(f2.y, kk);
        const float s3x = rl_f(f3.x, kk), s3y = rl_f(f3.y, kk);
        a0.x += s0x * wa.x + s0y * wb.x;  a0.y += s0x * wa.y + s0y * wb.y;
        a1.x += s1x * wa.x + s1y * wb.x;  a1.y += s1x * wa.y + s1y * wb.y;
        a2.x += s2x * wa.x + s2y * wb.x;  a2.y += s2x * wa.y + s2y * wb.y;
        a3.x += s3x * wa.x + s3y * wb.x;  a3.y += s3x * wa.y + s3y * wb.y;
    }

    ushort2 o;
    o.x = f2bf(a0.x); o.y = f2bf(a0.y); FWb2[(size_t)(m0 + 0) * 64 + lane] = o;
    o.x = f2bf(a1.x); o.y = f2bf(a1.y); FWb2[(size_t)(m0 + 1) * 64 + lane] = o;
    o.x = f2bf(a2.x); o.y = f2bf(a2.y); FWb2[(size_t)(m0 + 2) * 64 + lane] = o;
    o.x = f2bf(a3.x); o.y = f2bf(a3.y); FWb2[(size_t)(m0 + 3) * 64 + lane] = o;
}

// ---------- Fused: wave-per-node, barrier-free, LDS-free (round-5 structure). ----------
// Phase A (per 64-pair chunk): lane l computes w for pair base+l (2 dist gathers).
// Phase B: readlane-broadcast packed (i<<14|j) and w -> SGPRs; each lane accumulates
// dims {2*lane, 2*lane+1} from ushort2 FW rows (L2-resident).
__global__ __launch_bounds__(256, 8)
void fused_seg_kernel(const float* __restrict__ dist,
                      const ushort2* __restrict__ FW2,   // [N_NODES][64]
                      const int* __restrict__ seg,
                      const int* __restrict__ pair_i,
                      const int* __restrict__ pair_j,
                      const float* __restrict__ pair_cos,
                      const float* __restrict__ b,
                      float* __restrict__ out)
{
    const int wid  = threadIdx.x >> 6;
    const int lane = threadIdx.x & 63;
    const int n    = blockIdx.x * 4 + wid;     // grid = 2500 x 4 waves = 10000
    const int lo = seg[n];
    const int hi = seg[n + 1];
    const size_t drow = (size_t)n * N_NODES;

    float a0 = 0.f, a1 = 0.f;

    for (int base = lo; base < hi; base += 64) {
        // ---- phase A: this lane's pair weight ----
        const int p = base + lane;
        unsigned ijl = 0; float wl = 0.f;
        if (p < hi) {
            const int i = pair_i[p];
            const int j = pair_j[p];
            ijl = ((unsigned)i << 14) | (unsigned)j;
            wl  = pair_cos[p] * dist[drow + i] * dist[drow + j];
        }

        // ---- phase B: broadcast each pair, gather FW rows, accumulate ----
        const int qmax = min(64, hi - base);
        if (qmax == 64) {
            #pragma unroll 8
            for (int q = 0; q < 64; ++q) {
                const unsigned ijq = (unsigned)__builtin_amdgcn_readlane((int)ijl, q);
                const float    wq  = rl_f(wl, q);
                const int iq = (int)(ijq >> 14);
                const int jq = (int)(ijq & 16383u);
                const ushort2 fi = FW2[(size_t)iq * 64 + lane];
                const ushort2 fj = FW2[(size_t)jq * 64 + lane];
                a0 += wq * (bf2f(fi.x) + bf2f(fj.x));
                a1 += wq * (bf2f(fi.y) + bf2f(fj.y));
            }
        } else {
            #pragma unroll 4
            for (int q = 0; q < qmax; ++q) {
                const unsigned ijq = (unsigned)__builtin_amdgcn_readlane((int)ijl, q);
                const float    wq  = rl_f(wl, q);
                const int iq = (int)(ijq >> 14);
                const int jq = (int)(ijq & 16383u);
                const ushort2 fi = FW2[(size_t)iq * 64 + lane];
                const ushort2 fj = FW2[(size_t)jq * 64 + lane];
                a0 += wq * (bf2f(fi.x) + bf2f(fj.x));
                a1 += wq * (bf2f(fi.y) + bf2f(fj.y));
            }
        }
    }

    const float2 bb = ((const float2*)b)[lane];
    ((float2*)out)[(size_t)n * 64 + lane] = make_float2(a0 + bb.x, a1 + bb.y);
}

extern "C" void kernel_launch(void* const* d_in, const int* in_sizes, int n_in,
                              void* d_out, int out_size, void* d_ws, size_t ws_size,
                              hipStream_t stream) {
    const float* features  = (const float*)d_in[0];
    const float* dist      = (const float*)d_in[1];
    const int*   pair_node = (const int*)  d_in[2];
    const int*   pair_i    = (const int*)  d_in[3];
    const int*   pair_j    = (const int*)  d_in[4];
    const float* pair_cos  = (const float*)d_in[5];
    const float* W         = (const float*)d_in[6];
    const float* b         = (const float*)d_in[7];
    float* out = (float*)d_out;

    // workspace: seg int[N_NODES+1] (padded to 40960 B), then FW bf16 (2.56 MB)
    int* seg = (int*)d_ws;
    ushort2* FWb2 = (ushort2*)((char*)d_ws + 10240 * sizeof(int));

    prep_kernel<<<SEG_BLOCKS + FW_BLOCKS, 256, 0, stream>>>(pair_node, seg, features, W, FWb2);
    fused_seg_kernel<<<N_NODES / 4, 256, 0, stream>>>(
        dist, FWb2, seg, pair_i, pair_j, pair_cos, b, out);
}